// Round 13
// baseline (1294.182 us; speedup 1.0000x reference)
//
#include <hip/hip_runtime.h>
#include <hip/hip_bf16.h>

#define Bn 64
#define Tn 512
#define En 128
#define Hn 64
#define Gn 256   // 4*H
#define Cn 20

typedef float f32x2 __attribute__((ext_vector_type(2)));

__device__ __forceinline__ float sigf(float x)      { return 1.f/(1.f+__expf(-x)); }
__device__ __forceinline__ float tanhfast(float x)  { return 2.f/(1.f+__expf(-2.f*x)) - 1.f; }

// ---------------------------------------------------------------------------
// Kernel A: Z0[b*T+t][j] = (word_emb[ids[b,t]] + pos_emb[t]) @ Wx_b0 + b_b0
// ---------------------------------------------------------------------------
__global__ __launch_bounds__(256, 1) void emb_proj_kernel(
    const int* __restrict__ x, const float* __restrict__ word_emb,
    const float* __restrict__ pos_emb, const float* __restrict__ wx,
    const float* __restrict__ bias, float* __restrict__ z0)
{
  __shared__ float emb[64][En];     // 32 KB
  __shared__ float wxl[32][Gn];     // 32 KB
  const int tid  = threadIdx.x;
  const int row0 = blockIdx.x * 64;

  #pragma unroll
  for (int it = 0; it < 8; ++it) {
    int idx = it*256 + tid;
    int rr  = idx >> 5;
    int e4  = (idx & 31) << 2;
    int r   = row0 + rr;
    int b   = r >> 9;
    int t   = r & (Tn-1);
    int id  = x[b*3*Tn + t];
    float4 we = *reinterpret_cast<const float4*>(&word_emb[(size_t)id*En + e4]);
    float4 pe = *reinterpret_cast<const float4*>(&pos_emb[(size_t)t*En + e4]);
    *reinterpret_cast<float4*>(&emb[rr][e4]) =
        make_float4(we.x+pe.x, we.y+pe.y, we.z+pe.z, we.w+pe.w);
  }

  const int jc = tid & 63;
  const int rg = tid >> 6;
  float acc[16][4];
  float4 bb = *reinterpret_cast<const float4*>(&bias[jc*4]);
  #pragma unroll
  for (int r = 0; r < 16; ++r) { acc[r][0]=bb.x; acc[r][1]=bb.y; acc[r][2]=bb.z; acc[r][3]=bb.w; }

  for (int ec = 0; ec < 4; ++ec) {
    __syncthreads();
    #pragma unroll
    for (int it = 0; it < 8; ++it) {
      int idx = it*256 + tid;
      int ee  = idx >> 6;
      int j4  = (idx & 63) << 2;
      *reinterpret_cast<float4*>(&wxl[ee][j4]) =
          *reinterpret_cast<const float4*>(&wx[(size_t)(ec*32+ee)*Gn + j4]);
    }
    __syncthreads();
    for (int ee = 0; ee < 32; ++ee) {
      float4 w = *reinterpret_cast<const float4*>(&wxl[ee][jc*4]);
      #pragma unroll
      for (int r = 0; r < 16; ++r) {
        float xv = emb[rg*16+r][ec*32+ee];
        acc[r][0] = fmaf(xv, w.x, acc[r][0]);
        acc[r][1] = fmaf(xv, w.y, acc[r][1]);
        acc[r][2] = fmaf(xv, w.z, acc[r][2]);
        acc[r][3] = fmaf(xv, w.w, acc[r][3]);
      }
    }
  }
  #pragma unroll
  for (int r = 0; r < 16; ++r) {
    size_t row = (size_t)row0 + rg*16 + r;
    *reinterpret_cast<float4*>(&z0[row*Gn + jc*4]) =
        make_float4(acc[r][0], acc[r][1], acc[r][2], acc[r][3]);
  }
}

// ---------------------------------------------------------------------------
// Kernel A2: ZX1[b*T+t][j] = hb0[b,t,:] @ Wx_b1 + b_b1
// ---------------------------------------------------------------------------
__global__ __launch_bounds__(256, 1) void zx1_gemm_kernel(
    const float* __restrict__ hb0, const float* __restrict__ wx,
    const float* __restrict__ bias, float* __restrict__ zx1)
{
  __shared__ float xl[64][Hn];
  __shared__ float wl[32][Gn];
  const int tid  = threadIdx.x;
  const int row0 = blockIdx.x * 64;

  #pragma unroll
  for (int it = 0; it < 4; ++it) {
    int idx = it*256 + tid;
    int rr  = idx >> 4;
    int e4  = (idx & 15) << 2;
    *reinterpret_cast<float4*>(&xl[rr][e4]) =
        *reinterpret_cast<const float4*>(&hb0[((size_t)row0+rr)*Hn + e4]);
  }

  const int jc = tid & 63;
  const int rg = tid >> 6;
  float acc[16][4];
  float4 bb = *reinterpret_cast<const float4*>(&bias[jc*4]);
  #pragma unroll
  for (int r = 0; r < 16; ++r) { acc[r][0]=bb.x; acc[r][1]=bb.y; acc[r][2]=bb.z; acc[r][3]=bb.w; }

  for (int kc = 0; kc < 2; ++kc) {
    __syncthreads();
    #pragma unroll
    for (int it = 0; it < 8; ++it) {
      int idx = it*256 + tid;
      int kk  = idx >> 6;
      int j4  = (idx & 63) << 2;
      *reinterpret_cast<float4*>(&wl[kk][j4]) =
          *reinterpret_cast<const float4*>(&wx[(size_t)(kc*32+kk)*Gn + j4]);
    }
    __syncthreads();
    for (int kk = 0; kk < 32; ++kk) {
      float4 w = *reinterpret_cast<const float4*>(&wl[kk][jc*4]);
      #pragma unroll
      for (int r = 0; r < 16; ++r) {
        float xv = xl[rg*16+r][kc*32+kk];
        acc[r][0] = fmaf(xv, w.x, acc[r][0]);
        acc[r][1] = fmaf(xv, w.y, acc[r][1]);
        acc[r][2] = fmaf(xv, w.z, acc[r][2]);
        acc[r][3] = fmaf(xv, w.w, acc[r][3]);
      }
    }
  }
  #pragma unroll
  for (int r = 0; r < 16; ++r) {
    size_t row = (size_t)row0 + rg*16 + r;
    *reinterpret_cast<float4*>(&zx1[row*Gn + jc*4]) =
        make_float4(acc[r][0], acc[r][1], acc[r][2], acc[r][3]);
  }
}

// ---------------------------------------------------------------------------
// Recurrence: ONE wave per batch element; lane l owns h-lane l and its own 4
// gate columns {l, 64+l, 128+l, 192+l}. No barriers, no z exchange; 16
// uniform ds_read_b128 per step (R11: the 4-wave variant's 64 LDS reads/step
// saturate the shared per-CU LDS pipe -- the real plateau). 128 v_pk_fma_f32
// per step. Weights: 256 floats via EARLY-CLOBBERED asm global_load defs
// (R12's fault: multi-load asm blobs without "=&v" let an output alias the
// address pair -> clobbered pointer under VMEM backpressure -> wild address).
// Packed to f32x2 after a per-pair vmcnt(0) + sched_barrier(0) (rule #18).
// amdgpu_waves_per_eu(1,1) lifts the VGPR budget (R11: 52->132 on demand;
// m08: no spill through ~450).
// ---------------------------------------------------------------------------
#define PK_FMA(acc, hp, wp) \
  asm("v_pk_fma_f32 %0, %1, %2, %0" : "+v"(acc) : "v"(hp), "v"(wp))

// pair p = Wh rows {2p, 2p+1}, this lane's 4 gate columns. 8 early-clobbered
// loads off one base pointer; offsets: col(+0/+64/+128/+192 floats) x row(+0/+1).
#define DECLWP(p)                                                            \
  f32x2 wi##p, wf##p, wg##p, wo##p;                                          \
  { float t0_,t1_,t2_,t3_,t4_,t5_,t6_,t7_;                                   \
    const float* pb_ = wh + (size_t)(2*(p))*Gn + l;                          \
    asm volatile("global_load_dword %0, %8, off\n\t"                         \
                 "global_load_dword %1, %8, off offset:1024\n\t"             \
                 "global_load_dword %2, %8, off offset:256\n\t"              \
                 "global_load_dword %3, %8, off offset:1280\n\t"             \
                 "global_load_dword %4, %8, off offset:512\n\t"              \
                 "global_load_dword %5, %8, off offset:1536\n\t"             \
                 "global_load_dword %6, %8, off offset:768\n\t"              \
                 "global_load_dword %7, %8, off offset:1792"                 \
                 : "=&v"(t0_), "=&v"(t1_), "=&v"(t2_), "=&v"(t3_),           \
                   "=&v"(t4_), "=&v"(t5_), "=&v"(t6_), "=&v"(t7_)            \
                 : "v"(pb_));                                                \
    asm volatile("s_waitcnt vmcnt(0)" ::: "memory");                         \
    __builtin_amdgcn_sched_barrier(0);                                       \
    wi##p = f32x2{t0_, t1_}; wf##p = f32x2{t2_, t3_};                        \
    wg##p = f32x2{t4_, t5_}; wo##p = f32x2{t6_, t7_}; }

// pairs pa (h rows 2pa,2pa+1) and pb=pa+1: one b128 h read feeds 8 pk_fma
#define FMAQ(pa, pb)                                                         \
  { float4 hv = *reinterpret_cast<const float4*>(&h_lds[(pa)*2]);            \
    f32x2 h01 = {hv.x, hv.y}, h23 = {hv.z, hv.w};                            \
    PK_FMA(aI, h01, wi##pa); PK_FMA(aI, h23, wi##pb);                        \
    PK_FMA(aF, h01, wf##pa); PK_FMA(aF, h23, wf##pb);                        \
    PK_FMA(aG, h01, wg##pa); PK_FMA(aG, h23, wg##pb);                        \
    PK_FMA(aO, h01, wo##pa); PK_FMA(aO, h23, wo##pb); }

template<bool IS_B0>
__global__ __attribute__((amdgpu_flat_work_group_size(64, 64),
                          amdgpu_waves_per_eu(1, 1)))
void lstm_wave(
    const int* __restrict__ x, const float* __restrict__ z,
    const float* __restrict__ wh, float* __restrict__ hb0,
    const float* __restrict__ dw, const float* __restrict__ db,
    float* __restrict__ out)
{
  const int b = blockIdx.x;
  const int l = threadIdx.x;        // 0..63, one wave
  __shared__ __align__(16) float h_lds[Hn];
  __shared__ float sm0[32], sm1[32];

  // len = sum(mask) via per-lane partial + wave butterfly (mask 1s-then-0s)
  int msum = 0;
  #pragma unroll
  for (int i = 0; i < 8; ++i) msum += x[b*3*Tn + 2*Tn + i*64 + l];
  #pragma unroll
  for (int off = 1; off < 64; off <<= 1) msum += __shfl_xor(msum, off, 64);
  const int len = msum;             // in [128, 512]

  h_lds[l] = 0.f;
  float c = 0.f, h = 0.f;
  const float* zr   = z   + (size_t)b*Tn*Gn;
  float*       hout = hb0 + (size_t)b*Tn*Hn;

  if (IS_B0) {
    // rows [len, T-1] of hout must be 0 (ZX1 gemm reads all rows)
    for (int r = len + (l >> 4); r < Tn; r += 4)
      *reinterpret_cast<float4*>(&hout[(size_t)r*Hn + (l & 15)*4]) =
          make_float4(0.f, 0.f, 0.f, 0.f);
  }

  // 128 weight pairs, each self-drained (one-time prologue cost)
  DECLWP(0)  DECLWP(1)  DECLWP(2)  DECLWP(3)
  DECLWP(4)  DECLWP(5)  DECLWP(6)  DECLWP(7)
  DECLWP(8)  DECLWP(9)  DECLWP(10) DECLWP(11)
  DECLWP(12) DECLWP(13) DECLWP(14) DECLWP(15)
  DECLWP(16) DECLWP(17) DECLWP(18) DECLWP(19)
  DECLWP(20) DECLWP(21) DECLWP(22) DECLWP(23)
  DECLWP(24) DECLWP(25) DECLWP(26) DECLWP(27)
  DECLWP(28) DECLWP(29) DECLWP(30) DECLWP(31)

  // depth-2 z prefetch; single-load blobs only (self-alias safe)
  float za0, za1, za2, za3, zb0, zb1, zb2, zb3;
  {
    const float* p = zr + (size_t)(IS_B0 ? len-1 : Tn-len)*Gn + l;
    asm volatile("global_load_dword %0, %1, off"            : "=v"(za0) : "v"(p));
    asm volatile("global_load_dword %0, %1, off offset:256" : "=v"(za1) : "v"(p));
    asm volatile("global_load_dword %0, %1, off offset:512" : "=v"(za2) : "v"(p));
    asm volatile("global_load_dword %0, %1, off offset:768" : "=v"(za3) : "v"(p));
  }
  {
    const float* p = zr + (size_t)(IS_B0 ? len-2 : Tn-len+1)*Gn + l;
    asm volatile("global_load_dword %0, %1, off"            : "=v"(zb0) : "v"(p));
    asm volatile("global_load_dword %0, %1, off offset:256" : "=v"(zb1) : "v"(p));
    asm volatile("global_load_dword %0, %1, off offset:512" : "=v"(zb2) : "v"(p));
    asm volatile("global_load_dword %0, %1, off offset:768" : "=v"(zb3) : "v"(p));
  }
  // prologue drain: zero-fill stores + first 2 z rows
  asm volatile("s_waitcnt vmcnt(0)" ::: "memory");
  __builtin_amdgcn_sched_barrier(0);

#define STEP(s_, Z0, Z1, Z2, Z3)                                             \
  {                                                                          \
    if (IS_B0) asm volatile("s_waitcnt vmcnt(5)" ::: "memory");              \
    else       asm volatile("s_waitcnt vmcnt(4)" ::: "memory");              \
    __builtin_amdgcn_sched_barrier(0);                                       \
    f32x2 aI = {Z0, 0.f}, aF = {Z1, 0.f}, aG = {Z2, 0.f}, aO = {Z3, 0.f};    \
    FMAQ(0,1)   FMAQ(2,3)   FMAQ(4,5)   FMAQ(6,7)                            \
    FMAQ(8,9)   FMAQ(10,11) FMAQ(12,13) FMAQ(14,15)                          \
    FMAQ(16,17) FMAQ(18,19) FMAQ(20,21) FMAQ(22,23)                          \
    FMAQ(24,25) FMAQ(26,27) FMAQ(28,29) FMAQ(30,31)                          \
    float a_i = aI[0]+aI[1], a_f = aF[0]+aF[1];                              \
    float a_g = aG[0]+aG[1], a_o = aO[0]+aO[1];                              \
    float ig = sigf(a_i), fg = sigf(a_f);                                    \
    float gg = tanhfast(a_g), og = sigf(a_o);                                \
    float cn_ = fmaf(fg, c, ig*gg);                                          \
    float hn_ = og * tanhfast(cn_);                                          \
    bool act_ = (s_) < len;                                                  \
    c = act_ ? cn_ : c;                                                      \
    h = act_ ? hn_ : h;                                                      \
    h_lds[l] = h;                                                            \
    if (IS_B0) {                                                             \
      int ts_ = len-1-(s_); ts_ = ts_ < 0 ? 0 : ts_;                         \
      float* sp_ = hout + (size_t)ts_*Hn + l;                                \
      asm volatile("global_store_dword %0, %1, off" :: "v"(sp_), "v"(h));    \
    }                                                                        \
    {                                                                        \
      int tn_ = IS_B0 ? (len-3-(s_)) : (Tn-len+(s_)+2);                      \
      tn_ = tn_ < 0 ? 0 : (tn_ > Tn-1 ? Tn-1 : tn_);                         \
      const float* p_ = zr + (size_t)tn_*Gn + l;                             \
      asm volatile("global_load_dword %0, %1, off"            : "=v"(Z0) : "v"(p_)); \
      asm volatile("global_load_dword %0, %1, off offset:256" : "=v"(Z1) : "v"(p_)); \
      asm volatile("global_load_dword %0, %1, off offset:512" : "=v"(Z2) : "v"(p_)); \
      asm volatile("global_load_dword %0, %1, off offset:768" : "=v"(Z3) : "v"(p_)); \
    }                                                                        \
  }

  const int lenr = (len + 1) & ~1;
  for (int s = 0; s < lenr; s += 2) {
    STEP(s+0, za0, za1, za2, za3);
    STEP(s+1, zb0, zb1, zb2, zb3);
  }
#undef STEP

  // drain asm VMEM; keep async-written regs alive past the drain (R5 lesson)
  asm volatile("s_waitcnt vmcnt(0)" ::: "memory");
  asm volatile("" :: "v"(za0), "v"(za1), "v"(za2), "v"(za3),
                     "v"(zb0), "v"(zb1), "v"(zb2), "v"(zb3));
  __builtin_amdgcn_sched_barrier(0);

  if (!IS_B0) {
    // head: logits (C=20) + softmax; single wave, in-order DS pipe
    if (l < Cn) {
      float lg = db[l];
      #pragma unroll
      for (int k = 0; k < Hn; ++k) lg = fmaf(h_lds[k], dw[k*Cn + l], lg);
      sm0[l] = lg;
    }
    if (l < Cn) {
      float m = sm0[0];
      #pragma unroll
      for (int k = 1; k < Cn; ++k) m = fmaxf(m, sm0[k]);
      float e = __expf(sm0[l] - m);
      sm1[l] = e;
      float ssum = 0.f;
      #pragma unroll
      for (int k = 0; k < Cn; ++k) ssum += sm1[k];
      out[b*Cn + l] = e / ssum;
    }
  }
}

// ---------------------------------------------------------------------------
extern "C" void kernel_launch(void* const* d_in, const int* in_sizes, int n_in,
                              void* d_out, int out_size, void* d_ws, size_t ws_size,
                              hipStream_t stream)
{
  const int*   x        = (const int*)  d_in[0];
  const float* word_emb = (const float*)d_in[1];
  const float* pos_emb  = (const float*)d_in[2];
  // forward-branch weights d_in[3..8] are dead code in the reference
  const float* wx_b0    = (const float*)d_in[9];
  const float* wh_b0    = (const float*)d_in[10];
  const float* b_b0     = (const float*)d_in[11];
  const float* wx_b1    = (const float*)d_in[12];
  const float* wh_b1    = (const float*)d_in[13];
  const float* b_b1     = (const float*)d_in[14];
  const float* dw       = (const float*)d_in[15];
  const float* db       = (const float*)d_in[16];
  float* out = (float*)d_out;

  float* z0  = (float*)d_ws;                    // B*T*256 f32 = 32 MiB (reused as ZX1)
  float* hb0 = z0 + (size_t)Bn*Tn*Gn;           // B*T*64  f32 =  8 MiB

  emb_proj_kernel<<<dim3((Bn*Tn)/64), dim3(256), 0, stream>>>(
      x, word_emb, pos_emb, wx_b0, b_b0, z0);
  lstm_wave<true><<<dim3(Bn), dim3(64), 0, stream>>>(
      x, z0, wh_b0, hb0, nullptr, nullptr, nullptr);
  zx1_gemm_kernel<<<dim3((Bn*Tn)/64), dim3(256), 0, stream>>>(
      hb0, wx_b1, b_b1, z0);                    // z0 buffer reused as ZX1
  lstm_wave<false><<<dim3(Bn), dim3(64), 0, stream>>>(
      x, z0, wh_b1, hb0, dw, db, out);
}

// Round 14
// 599.468 us; speedup vs baseline: 2.1589x; 2.1589x over previous
//
#include <hip/hip_runtime.h>
#include <hip/hip_bf16.h>

#define Bn 64
#define Tn 512
#define En 128
#define Hn 64
#define Gn 256   // 4*H
#define Cn 20

typedef float f32x2 __attribute__((ext_vector_type(2)));

__device__ __forceinline__ float sigf(float x)      { return 1.f/(1.f+__expf(-x)); }
__device__ __forceinline__ float tanhfast(float x)  { return 2.f/(1.f+__expf(-2.f*x)) - 1.f; }

// ---------------------------------------------------------------------------
// Kernel A: Z0[b*T+t][j] = (word_emb[ids[b,t]] + pos_emb[t]) @ Wx_b0 + b_b0
// ---------------------------------------------------------------------------
__global__ __launch_bounds__(256, 1) void emb_proj_kernel(
    const int* __restrict__ x, const float* __restrict__ word_emb,
    const float* __restrict__ pos_emb, const float* __restrict__ wx,
    const float* __restrict__ bias, float* __restrict__ z0)
{
  __shared__ float emb[64][En];     // 32 KB
  __shared__ float wxl[32][Gn];     // 32 KB
  const int tid  = threadIdx.x;
  const int row0 = blockIdx.x * 64;

  #pragma unroll
  for (int it = 0; it < 8; ++it) {
    int idx = it*256 + tid;
    int rr  = idx >> 5;
    int e4  = (idx & 31) << 2;
    int r   = row0 + rr;
    int b   = r >> 9;
    int t   = r & (Tn-1);
    int id  = x[b*3*Tn + t];
    float4 we = *reinterpret_cast<const float4*>(&word_emb[(size_t)id*En + e4]);
    float4 pe = *reinterpret_cast<const float4*>(&pos_emb[(size_t)t*En + e4]);
    *reinterpret_cast<float4*>(&emb[rr][e4]) =
        make_float4(we.x+pe.x, we.y+pe.y, we.z+pe.z, we.w+pe.w);
  }

  const int jc = tid & 63;
  const int rg = tid >> 6;
  float acc[16][4];
  float4 bb = *reinterpret_cast<const float4*>(&bias[jc*4]);
  #pragma unroll
  for (int r = 0; r < 16; ++r) { acc[r][0]=bb.x; acc[r][1]=bb.y; acc[r][2]=bb.z; acc[r][3]=bb.w; }

  for (int ec = 0; ec < 4; ++ec) {
    __syncthreads();
    #pragma unroll
    for (int it = 0; it < 8; ++it) {
      int idx = it*256 + tid;
      int ee  = idx >> 6;
      int j4  = (idx & 63) << 2;
      *reinterpret_cast<float4*>(&wxl[ee][j4]) =
          *reinterpret_cast<const float4*>(&wx[(size_t)(ec*32+ee)*Gn + j4]);
    }
    __syncthreads();
    for (int ee = 0; ee < 32; ++ee) {
      float4 w = *reinterpret_cast<const float4*>(&wxl[ee][jc*4]);
      #pragma unroll
      for (int r = 0; r < 16; ++r) {
        float xv = emb[rg*16+r][ec*32+ee];
        acc[r][0] = fmaf(xv, w.x, acc[r][0]);
        acc[r][1] = fmaf(xv, w.y, acc[r][1]);
        acc[r][2] = fmaf(xv, w.z, acc[r][2]);
        acc[r][3] = fmaf(xv, w.w, acc[r][3]);
      }
    }
  }
  #pragma unroll
  for (int r = 0; r < 16; ++r) {
    size_t row = (size_t)row0 + rg*16 + r;
    *reinterpret_cast<float4*>(&z0[row*Gn + jc*4]) =
        make_float4(acc[r][0], acc[r][1], acc[r][2], acc[r][3]);
  }
}

// ---------------------------------------------------------------------------
// Kernel A2: ZX1[b*T+t][j] = hb0[b,t,:] @ Wx_b1 + b_b1
// ---------------------------------------------------------------------------
__global__ __launch_bounds__(256, 1) void zx1_gemm_kernel(
    const float* __restrict__ hb0, const float* __restrict__ wx,
    const float* __restrict__ bias, float* __restrict__ zx1)
{
  __shared__ float xl[64][Hn];
  __shared__ float wl[32][Gn];
  const int tid  = threadIdx.x;
  const int row0 = blockIdx.x * 64;

  #pragma unroll
  for (int it = 0; it < 4; ++it) {
    int idx = it*256 + tid;
    int rr  = idx >> 4;
    int e4  = (idx & 15) << 2;
    *reinterpret_cast<float4*>(&xl[rr][e4]) =
        *reinterpret_cast<const float4*>(&hb0[((size_t)row0+rr)*Hn + e4]);
  }

  const int jc = tid & 63;
  const int rg = tid >> 6;
  float acc[16][4];
  float4 bb = *reinterpret_cast<const float4*>(&bias[jc*4]);
  #pragma unroll
  for (int r = 0; r < 16; ++r) { acc[r][0]=bb.x; acc[r][1]=bb.y; acc[r][2]=bb.z; acc[r][3]=bb.w; }

  for (int kc = 0; kc < 2; ++kc) {
    __syncthreads();
    #pragma unroll
    for (int it = 0; it < 8; ++it) {
      int idx = it*256 + tid;
      int kk  = idx >> 6;
      int j4  = (idx & 63) << 2;
      *reinterpret_cast<float4*>(&wl[kk][j4]) =
          *reinterpret_cast<const float4*>(&wx[(size_t)(kc*32+kk)*Gn + j4]);
    }
    __syncthreads();
    for (int kk = 0; kk < 32; ++kk) {
      float4 w = *reinterpret_cast<const float4*>(&wl[kk][jc*4]);
      #pragma unroll
      for (int r = 0; r < 16; ++r) {
        float xv = xl[rg*16+r][kc*32+kk];
        acc[r][0] = fmaf(xv, w.x, acc[r][0]);
        acc[r][1] = fmaf(xv, w.y, acc[r][1]);
        acc[r][2] = fmaf(xv, w.z, acc[r][2]);
        acc[r][3] = fmaf(xv, w.w, acc[r][3]);
      }
    }
  }
  #pragma unroll
  for (int r = 0; r < 16; ++r) {
    size_t row = (size_t)row0 + rg*16 + r;
    *reinterpret_cast<float4*>(&zx1[row*Gn + jc*4]) =
        make_float4(acc[r][0], acc[r][1], acc[r][2], acc[r][3]);
  }
}

// ---------------------------------------------------------------------------
// Recurrence: TWO waves per batch element, split by K (not by gate).
// Wave wv covers k in [wv*32, wv*32+32); lane l accumulates partial dot
// products for ALL 4 gate columns {l,64+l,128+l,192+l} over its k-half.
// Design space mapped by R8/R11/R13: 1 wave x 256 w/lane busts the 256-VGPR
// architectural cap (R13: pegged 256 + scratch); 4 waves x 64 w/lane fits
// but pays 64 LDS ops + 4-wave barrier + z exchange per step (R8: 1250cy).
// 2 waves x 128 w/lane (~180 VGPR) fits AND halves every per-step cost:
// 8 uniform ds_read_b128 per wave (own h copy, own k-half), one float4
// partial exchange via parity-double-buffered LDS + single lgkm-only
// barrier, 64 v_pk_fma_f32. Both waves redundantly finish the gates so h
// stays wave-private. All R5/R12 asm-hazard fixes retained.
// ---------------------------------------------------------------------------
#define WAVE_BARRIER()                                        \
  do {                                                        \
    asm volatile("s_waitcnt lgkmcnt(0)" ::: "memory");        \
    __builtin_amdgcn_sched_barrier(0);                        \
    __builtin_amdgcn_s_barrier();                             \
    __builtin_amdgcn_sched_barrier(0);                        \
  } while (0)

#define PK_FMA(acc, hp, wp) \
  asm("v_pk_fma_f32 %0, %1, %2, %0" : "+v"(acc) : "v"(hp), "v"(wp))

// pair p = Wh rows {wk0+2p, wk0+2p+1}, this lane's 4 gate columns.
// 8 early-clobbered loads (R12 fix) + per-pair drain (rule #18).
#define DECLWP(p)                                                            \
  f32x2 wi##p, wf##p, wg##p, wo##p;                                          \
  { float t0_,t1_,t2_,t3_,t4_,t5_,t6_,t7_;                                   \
    const float* pb_ = wh + (size_t)(wk0 + 2*(p))*Gn + l;                    \
    asm volatile("global_load_dword %0, %8, off\n\t"                         \
                 "global_load_dword %1, %8, off offset:1024\n\t"             \
                 "global_load_dword %2, %8, off offset:256\n\t"              \
                 "global_load_dword %3, %8, off offset:1280\n\t"             \
                 "global_load_dword %4, %8, off offset:512\n\t"              \
                 "global_load_dword %5, %8, off offset:1536\n\t"             \
                 "global_load_dword %6, %8, off offset:768\n\t"              \
                 "global_load_dword %7, %8, off offset:1792"                 \
                 : "=&v"(t0_), "=&v"(t1_), "=&v"(t2_), "=&v"(t3_),           \
                   "=&v"(t4_), "=&v"(t5_), "=&v"(t6_), "=&v"(t7_)            \
                 : "v"(pb_));                                                \
    asm volatile("s_waitcnt vmcnt(0)" ::: "memory");                         \
    __builtin_amdgcn_sched_barrier(0);                                       \
    wi##p = f32x2{t0_, t1_}; wf##p = f32x2{t2_, t3_};                        \
    wg##p = f32x2{t4_, t5_}; wo##p = f32x2{t6_, t7_}; }

// slice j: h[wk0+4j .. wk0+4j+3] (one uniform b128) feeds pairs pa=2j, pb=2j+1
#define FMAQ(j, pa, pb)                                                      \
  { float4 hv = *reinterpret_cast<const float4*>(&h_own[wv][wk0 + (j)*4]);   \
    f32x2 h01 = {hv.x, hv.y}, h23 = {hv.z, hv.w};                            \
    PK_FMA(aI, h01, wi##pa); PK_FMA(aI, h23, wi##pb);                        \
    PK_FMA(aF, h01, wf##pa); PK_FMA(aF, h23, wf##pb);                        \
    PK_FMA(aG, h01, wg##pa); PK_FMA(aG, h23, wg##pb);                        \
    PK_FMA(aO, h01, wo##pa); PK_FMA(aO, h23, wo##pb); }

template<bool IS_B0>
__global__ __attribute__((amdgpu_flat_work_group_size(128, 128),
                          amdgpu_waves_per_eu(1, 1)))
void lstm_wave2(
    const int* __restrict__ x, const float* __restrict__ z,
    const float* __restrict__ wh, float* __restrict__ hb0,
    const float* __restrict__ dw, const float* __restrict__ db,
    float* __restrict__ out)
{
  const int b   = blockIdx.x;
  const int tid = threadIdx.x;      // 0..127
  const int wv  = tid >> 6;         // 0 or 1
  const int l   = tid & 63;
  const int wk0 = wv * 32;          // this wave's k-range start

  __shared__ __align__(16) float h_own[2][Hn];       // per-wave h copy
  __shared__ __align__(16) float xch[2][2][Hn*4];    // parity x wave x 64 lanes x 4
  __shared__ float sm0[32], sm1[32];

  // len = sum(mask), butterfly per wave (mask is 1s-then-0s)
  int msum = 0;
  #pragma unroll
  for (int i = 0; i < 8; ++i) msum += x[b*3*Tn + 2*Tn + i*64 + l];
  #pragma unroll
  for (int off = 1; off < 64; off <<= 1) msum += __shfl_xor(msum, off, 64);
  const int len = msum;             // in [128, 512]

  h_own[wv][l] = 0.f;
  float c = 0.f, h = 0.f;
  const float* zr   = z   + (size_t)b*Tn*Gn;
  float*       hout = hb0 + (size_t)b*Tn*Hn;

  if (IS_B0) {
    // rows [len, T-1] of hout must be 0 (ZX1 gemm reads all rows)
    for (int r = len + (tid >> 4); r < Tn; r += 8)
      *reinterpret_cast<float4*>(&hout[(size_t)r*Hn + (tid & 15)*4]) =
          make_float4(0.f, 0.f, 0.f, 0.f);
  }

  // 64 weight pairs (128 VGPRs), each self-drained (one-time prologue cost)
  DECLWP(0)  DECLWP(1)  DECLWP(2)  DECLWP(3)
  DECLWP(4)  DECLWP(5)  DECLWP(6)  DECLWP(7)
  DECLWP(8)  DECLWP(9)  DECLWP(10) DECLWP(11)
  DECLWP(12) DECLWP(13) DECLWP(14) DECLWP(15)

  // z: wave0 loads cols {l, 64+l} (gates i,f); wave1 {128+l, 192+l} (g,o).
  // depth-2 prefetch; single-load blobs only (self-alias safe).
  const int zcol = wv*128 + l;
  float zA0, zA1, zB0, zB1;
  {
    const float* p = zr + (size_t)(IS_B0 ? len-1 : Tn-len)*Gn + zcol;
    asm volatile("global_load_dword %0, %1, off"            : "=v"(zA0) : "v"(p));
    asm volatile("global_load_dword %0, %1, off offset:256" : "=v"(zA1) : "v"(p));
  }
  {
    const float* p = zr + (size_t)(IS_B0 ? len-2 : Tn-len+1)*Gn + zcol;
    asm volatile("global_load_dword %0, %1, off"            : "=v"(zB0) : "v"(p));
    asm volatile("global_load_dword %0, %1, off offset:256" : "=v"(zB1) : "v"(p));
  }
  asm volatile("s_waitcnt vmcnt(0)" ::: "memory");
  __builtin_amdgcn_sched_barrier(0);

#define STEP(s_, Z0, Z1)                                                     \
  {                                                                          \
    if (IS_B0 && wv == 0) asm volatile("s_waitcnt vmcnt(4)" ::: "memory");   \
    else                  asm volatile("s_waitcnt vmcnt(2)" ::: "memory");   \
    __builtin_amdgcn_sched_barrier(0);                                       \
    f32x2 aI = {wv ? 0.f : Z0, 0.f}, aF = {wv ? 0.f : Z1, 0.f};              \
    f32x2 aG = {wv ? Z0 : 0.f, 0.f}, aO = {wv ? Z1 : 0.f, 0.f};              \
    FMAQ(0,0,1)   FMAQ(1,2,3)   FMAQ(2,4,5)   FMAQ(3,6,7)                    \
    FMAQ(4,8,9)   FMAQ(5,10,11) FMAQ(6,12,13) FMAQ(7,14,15)                  \
    { /* prefetch z for step s_+2 */                                         \
      int tn_ = IS_B0 ? (len-3-(s_)) : (Tn-len+(s_)+2);                      \
      tn_ = tn_ < 0 ? 0 : (tn_ > Tn-1 ? Tn-1 : tn_);                         \
      const float* p_ = zr + (size_t)tn_*Gn + zcol;                          \
      asm volatile("global_load_dword %0, %1, off"            : "=v"(Z0) : "v"(p_)); \
      asm volatile("global_load_dword %0, %1, off offset:256" : "=v"(Z1) : "v"(p_)); \
    }                                                                        \
    float4 mine = make_float4(aI[0]+aI[1], aF[0]+aF[1],                      \
                              aG[0]+aG[1], aO[0]+aO[1]);                     \
    *reinterpret_cast<float4*>(&xch[(s_)&1][wv][l*4]) = mine;                \
    WAVE_BARRIER();                                                          \
    float4 oth = *reinterpret_cast<const float4*>(&xch[(s_)&1][wv^1][l*4]);  \
    float ig = sigf(mine.x + oth.x);                                         \
    float fg = sigf(mine.y + oth.y);                                         \
    float gg = tanhfast(mine.z + oth.z);                                     \
    float og = sigf(mine.w + oth.w);                                         \
    float cn_ = fmaf(fg, c, ig*gg);                                          \
    float hn_ = og * tanhfast(cn_);                                          \
    bool act_ = (s_) < len;                                                  \
    c = act_ ? cn_ : c;                                                      \
    h = act_ ? hn_ : h;                                                      \
    h_own[wv][l] = h;                                                        \
    if (IS_B0 && wv == 0) {                                                  \
      int ts_ = len-1-(s_); ts_ = ts_ < 0 ? 0 : ts_;                         \
      float* sp_ = hout + (size_t)ts_*Hn + l;                                \
      asm volatile("global_store_dword %0, %1, off" :: "v"(sp_), "v"(h));    \
    }                                                                        \
  }

  const int lenr = (len + 1) & ~1;
  for (int s = 0; s < lenr; s += 2) {
    STEP(s+0, zA0, zA1);
    STEP(s+1, zB0, zB1);
  }
#undef STEP

  // drain asm VMEM; keep async-written regs alive past the drain (R5 lesson)
  asm volatile("s_waitcnt vmcnt(0)" ::: "memory");
  asm volatile("" :: "v"(zA0), "v"(zA1), "v"(zB0), "v"(zB1));
  __builtin_amdgcn_sched_barrier(0);

  if (!IS_B0) {
    // head: logits (C=20) + softmax; wave 0 only (own h copy is complete)
    if (tid < Cn) {
      float lg = db[tid];
      #pragma unroll
      for (int k = 0; k < Hn; ++k) lg = fmaf(h_own[0][k], dw[k*Cn + tid], lg);
      sm0[tid] = lg;
    }
    if (tid < Cn) {
      float m = sm0[0];
      #pragma unroll
      for (int k = 1; k < Cn; ++k) m = fmaxf(m, sm0[k]);
      float e = __expf(sm0[tid] - m);
      sm1[tid] = e;
      float ssum = 0.f;
      #pragma unroll
      for (int k = 0; k < Cn; ++k) ssum += sm1[k];
      out[b*Cn + tid] = e / ssum;
    }
  }
}

// ---------------------------------------------------------------------------
extern "C" void kernel_launch(void* const* d_in, const int* in_sizes, int n_in,
                              void* d_out, int out_size, void* d_ws, size_t ws_size,
                              hipStream_t stream)
{
  const int*   x        = (const int*)  d_in[0];
  const float* word_emb = (const float*)d_in[1];
  const float* pos_emb  = (const float*)d_in[2];
  // forward-branch weights d_in[3..8] are dead code in the reference
  const float* wx_b0    = (const float*)d_in[9];
  const float* wh_b0    = (const float*)d_in[10];
  const float* b_b0     = (const float*)d_in[11];
  const float* wx_b1    = (const float*)d_in[12];
  const float* wh_b1    = (const float*)d_in[13];
  const float* b_b1     = (const float*)d_in[14];
  const float* dw       = (const float*)d_in[15];
  const float* db       = (const float*)d_in[16];
  float* out = (float*)d_out;

  float* z0  = (float*)d_ws;                    // B*T*256 f32 = 32 MiB (reused as ZX1)
  float* hb0 = z0 + (size_t)Bn*Tn*Gn;           // B*T*64  f32 =  8 MiB

  emb_proj_kernel<<<dim3((Bn*Tn)/64), dim3(256), 0, stream>>>(
      x, word_emb, pos_emb, wx_b0, b_b0, z0);
  lstm_wave2<true><<<dim3(Bn), dim3(128), 0, stream>>>(
      x, z0, wh_b0, hb0, nullptr, nullptr, nullptr);
  zx1_gemm_kernel<<<dim3((Bn*Tn)/64), dim3(256), 0, stream>>>(
      hb0, wx_b1, b_b1, z0);                    // z0 buffer reused as ZX1
  lstm_wave2<false><<<dim3(Bn), dim3(128), 0, stream>>>(
      x, z0, wh_b1, hb0, dw, db, out);
}